// Round 7
// baseline (3357.471 us; speedup 1.0000x reference)
//
#include <hip/hip_runtime.h>
#include <math.h>

// ---------------- problem constants ----------------
#define B     16
#define C0    3
#define H0    510
#define W0    510
#define C1    18
#define C2    36
#define H     256
#define W     256
#define HW    65536          // 256*256
#define NSTAT 1048576        // B*HW, BN reduction count
#define EPS   1e-5f
#define LEAK  0.1f

// ws float offsets
#define X1_FLOATS   18874368   // B*C1*HW
#define OFF_BN1_SUM   0
#define OFF_BN1_SQ    18
#define OFF_BN1_SCALE 36
#define OFF_BN1_SHIFT 54
#define OFF_POOL1     72      // 16*18 = 288
#define OFF_S1        360     // 288
#define OFF_BN2_SUM   648
#define OFF_BN2_SQ    684
#define OFF_BN2_SCALE 720
#define OFF_BN2_SHIFT 756
#define OFF_POOL2     792     // 16*36 = 576
#define OFF_S2        1368    // 576
#define OFF_REVSUM    1944    // 576
#define STATS_TOTAL   2520

#define OUT_X2_FLOATS 37748736  // B*C2*HW

// Opaque zero in a VGPR: forces address arithmetic to be divergent-typed so
// the compiler emits vector-memory (vmcnt) loads for block-uniform weights
// instead of scalar (lgkmcnt) loads. Separating the counters lets LDS tap
// reads retire independently of the weight-load stream.
__device__ inline int opaque_zero() {
  int z;
  asm volatile("v_mov_b32 %0, 0" : "=v"(z));
  return z;
}

__device__ inline float wave_reduce_sum(float v) {
  #pragma unroll
  for (int off = 32; off > 0; off >>= 1) v += __shfl_down(v, off, 64);
  return v;
}

template<int NCH>
__device__ inline void block_stats(const float* acc, float* gsum, float* gsq) {
  __shared__ float smem_s[4][NCH];
  __shared__ float smem_q[4][NCH];
  const int tid = threadIdx.x, wave = tid >> 6, lane = tid & 63;
  #pragma unroll
  for (int o = 0; o < NCH; ++o) {
    float s = wave_reduce_sum(acc[o]);
    float q = wave_reduce_sum(acc[o] * acc[o]);
    if (lane == 0) { smem_s[wave][o] = s; smem_q[wave][o] = q; }
  }
  __syncthreads();
  if (tid < NCH) {
    atomicAdd(&gsum[tid], smem_s[0][tid] + smem_s[1][tid] + smem_s[2][tid] + smem_s[3][tid]);
    atomicAdd(&gsq[tid],  smem_q[0][tid] + smem_q[1][tid] + smem_q[2][tid] + smem_q[3][tid]);
  }
}

// ---------------- conv1: 3->18, 4x4, stride 2, pad 2, fused BN1 stats ----------------
// Writes RAW conv output (pre-BN). BN1 is applied on the fly by all consumers.
__global__ __launch_bounds__(256) void conv1_kernel(
    const float* __restrict__ x, const float* __restrict__ w,
    const float* __restrict__ bias, float* __restrict__ out,
    float* __restrict__ gsum, float* __restrict__ gsq)
{
  const int b = blockIdx.z;
  const int tid = threadIdx.x;
  const int ly = tid >> 4, lx = tid & 15;
  const int oy = blockIdx.y * 16 + ly;
  const int ox = blockIdx.x * 16 + lx;

  const float* wv = w + opaque_zero();   // VMEM weight path

  float acc[C1];
  #pragma unroll
  for (int o = 0; o < C1; ++o) acc[o] = bias[o];

  const float* xb = x + (size_t)b * C0 * H0 * W0;
  #pragma unroll
  for (int c = 0; c < C0; ++c) {
    float iv[16];
    #pragma unroll
    for (int ky = 0; ky < 4; ++ky) {
      const int iy = oy * 2 - 2 + ky;
      #pragma unroll
      for (int kx = 0; kx < 4; ++kx) {
        const int ix = ox * 2 - 2 + kx;
        const bool ok = (iy >= 0) && (iy < H0) && (ix >= 0) && (ix < W0);
        iv[ky * 4 + kx] = ok ? xb[c * (H0 * W0) + iy * W0 + ix] : 0.0f;
      }
    }
    #pragma unroll
    for (int o = 0; o < C1; ++o) {
      float a = acc[o];
      #pragma unroll
      for (int t = 0; t < 16; ++t) a = fmaf(iv[t], wv[o * 48 + c * 16 + t], a);
      acc[o] = a;
    }
  }

  float* ob = out + ((size_t)b * C1) * HW + oy * W + ox;
  #pragma unroll
  for (int o = 0; o < C1; ++o) ob[(size_t)o * HW] = acc[o];

  block_stats<C1>(acc, gsum, gsq);
}

// ---------------- BN finalize (both layers) ----------------
__global__ void finalize_bn_kernel(float* __restrict__ stats,
                                   const float* __restrict__ g, const float* __restrict__ be,
                                   int nch, int sum_off, int sq_off, int scale_off, int shift_off)
{
  const int t = threadIdx.x;
  if (t < nch) {
    const float inv_n = 1.0f / (float)NSTAT;
    float mean = stats[sum_off + t] * inv_n;
    float var  = stats[sq_off + t] * inv_n - mean * mean;
    float sc   = g[t] * rsqrtf(var + EPS);
    stats[scale_off + t] = sc;
    stats[shift_off + t] = be[t] - mean * sc;
  }
}

// ---------------- BN+leaky pool (compute-only, no write-back) ----------------
// pool[b,c] += sum over pixels of leaky_relu(raw*sc + sh)
__global__ __launch_bounds__(256) void bnpool_kernel(
    const float* __restrict__ buf, const float* __restrict__ scale,
    const float* __restrict__ shift, float* __restrict__ pool, int nch)
{
  const int c = blockIdx.y, b = blockIdx.z;
  const int tid = threadIdx.x;
  const size_t base = ((size_t)(b * nch + c)) * HW + blockIdx.x * 1024 + tid * 4;
  const float sc = scale[c], sh = shift[c];
  float4 v = *(const float4*)(buf + base);
  float r0 = fmaf(v.x, sc, sh); r0 = r0 > 0.0f ? r0 : LEAK * r0;
  float r1 = fmaf(v.y, sc, sh); r1 = r1 > 0.0f ? r1 : LEAK * r1;
  float r2 = fmaf(v.z, sc, sh); r2 = r2 > 0.0f ? r2 : LEAK * r2;
  float r3 = fmaf(v.w, sc, sh); r3 = r3 > 0.0f ? r3 : LEAK * r3;

  float s = wave_reduce_sum(r0 + r1 + r2 + r3);
  __shared__ float smem[4];
  const int wave = tid >> 6, lane = tid & 63;
  if (lane == 0) smem[wave] = s;
  __syncthreads();
  if (tid == 0) atomicAdd(&pool[b * nch + c], smem[0] + smem[1] + smem[2] + smem[3]);
}

// ---------------- SE1: hidden dim 1 ----------------
__global__ void se1_kernel(float* __restrict__ stats,
                           const float* __restrict__ w1, const float* __restrict__ w2)
{
  __shared__ float hid[B];
  const int t = threadIdx.x;
  if (t < B) {
    float h = 0.0f;
    for (int c = 0; c < C1; ++c)
      h += stats[OFF_POOL1 + t * C1 + c] * (1.0f / (float)HW) * w1[c];
    hid[t] = fmaxf(h, 0.0f);
  }
  __syncthreads();
  for (int i = t; i < B * C1; i += 64) {
    const int b = i / C1, c = i % C1;
    const float v = hid[b] * w2[c];
    stats[OFF_S1 + i] = 1.0f / (1.0f + expf(-v));
  }
}

// ---------------- conv2: 18->36, 3x3, pad 1 ----------------
// 1 px/thread, 16x16 tile, 2 passes of 18 output channels.
// Weights go through the vector-memory path (vmcnt) via opaque_zero so LDS
// tap reads retire on a clean lgkmcnt (R5: VALUBusy 37%, stall-bound on
// mixed SMEM+LDS lgkmcnt waits). Review 1x1 is hoisted out of the c-loop:
// centers saved to cent[], review FMAs run in a contiguous-load epilogue.
__global__ __launch_bounds__(256, 6) void conv2_kernel(
    const float* __restrict__ x1raw, const float* __restrict__ w,
    const float* __restrict__ bias, const float* __restrict__ sc1,
    const float* __restrict__ sh1, const float* __restrict__ s1,
    const float* __restrict__ rw, const float* __restrict__ rb,
    float* __restrict__ out, float* __restrict__ gsum, float* __restrict__ gsq,
    float* __restrict__ revsum)
{
  __shared__ float in_lds[C1 * 18 * 18];   // [c][iy][ix], BN1-applied, pre-s1
  __shared__ float red_s[4][18];
  __shared__ float red_q[4][18];
  __shared__ float red_r[4][18];

  const int b = blockIdx.z;
  const int ty0 = blockIdx.y * 16, tx0 = blockIdx.x * 16;
  const int tid = threadIdx.x;

  const float* xb = x1raw + (size_t)b * C1 * HW;
  for (int i = tid; i < C1 * 324; i += 256) {
    const int c = i / 324;
    const int rem = i - c * 324;
    const int r = rem / 18;
    const int col = rem - r * 18;
    const int gy = ty0 - 1 + r;
    const int gx = tx0 - 1 + col;
    float v = 0.0f;
    if (gy >= 0 && gy < H && gx >= 0 && gx < W) {
      v = fmaf(xb[c * HW + gy * W + gx], sc1[c], sh1[c]);
      v = v > 0.0f ? v : LEAK * v;           // this IS x1 (post-BN, pre-SE)
    }
    in_lds[i] = v;
  }
  __syncthreads();

  const int ly = tid >> 4, lx = tid & 15;
  const int wave = tid >> 6, lane = tid & 63;
  const float* s1b = s1 + b * C1;

  const float* wv  = w  + opaque_zero();   // VMEM weight paths
  const float* rwv = rw + opaque_zero();

  #pragma unroll 1
  for (int p = 0; p < 2; ++p) {            // channels [18p, 18p+18)
    const int ob18 = p * 18;
    float acc[18], racc[18], cent[C1];
    #pragma unroll
    for (int j = 0; j < 18; ++j) { acc[j] = bias[ob18 + j]; racc[j] = rb[ob18 + j]; }

    for (int c = 0; c < C1; ++c) {
      float iv[9];
      #pragma unroll
      for (int ky = 0; ky < 3; ++ky)
        #pragma unroll
        for (int kx = 0; kx < 3; ++kx)
          iv[ky * 3 + kx] = in_lds[c * 324 + (ly + ky) * 18 + (lx + kx)];

      cent[c] = iv[4];                     // center, pre-s1 (= x1) for review
      const float s1c = s1b[c];
      #pragma unroll
      for (int t = 0; t < 9; ++t) iv[t] *= s1c;

      const float* wc = wv + (size_t)ob18 * 162 + c * 9;   // block-uniform, VMEM
      #pragma unroll
      for (int j = 0; j < 18; ++j) {
        #pragma unroll
        for (int t = 0; t < 9; ++t)
          acc[j] = fmaf(iv[t], wc[j * 162 + t], acc[j]);
      }
    }

    // review 1x1 epilogue: contiguous rw rows, centers from registers
    #pragma unroll
    for (int j = 0; j < 18; ++j) {
      const float* rr = rwv + (size_t)(ob18 + j) * C1;
      float r = racc[j];
      #pragma unroll
      for (int c = 0; c < C1; ++c) r = fmaf(cent[c], rr[c], r);
      racc[j] = r;
    }

    // store this pass's 18 channels (coalesced across lx)
    float* ob = out + ((size_t)(b * C2 + ob18)) * HW + (ty0 + ly) * W + tx0 + lx;
    #pragma unroll
    for (int j = 0; j < 18; ++j) ob[(size_t)j * HW] = acc[j];

    // BN2 stats + review sums for these 18 channels
    __syncthreads();   // guard smem reuse across passes
    #pragma unroll
    for (int j = 0; j < 18; ++j) {
      float s  = wave_reduce_sum(acc[j]);
      float qq = wave_reduce_sum(acc[j] * acc[j]);
      float rs = wave_reduce_sum(fmaxf(racc[j], 0.0f));
      if (lane == 0) { red_s[wave][j] = s; red_q[wave][j] = qq; red_r[wave][j] = rs; }
    }
    __syncthreads();
    if (tid < 18) {
      atomicAdd(&gsum[ob18 + tid], red_s[0][tid] + red_s[1][tid] + red_s[2][tid] + red_s[3][tid]);
      atomicAdd(&gsq[ob18 + tid],  red_q[0][tid] + red_q[1][tid] + red_q[2][tid] + red_q[3][tid]);
      atomicAdd(&revsum[b * C2 + ob18 + tid],
                red_r[0][tid] + red_r[1][tid] + red_r[2][tid] + red_r[3][tid]);
    }
  }
}

// ---------------- SE2: hidden dim 2 ----------------
__global__ void se2_kernel(float* __restrict__ stats,
                           const float* __restrict__ w1, const float* __restrict__ w2)
{
  __shared__ float hid[B][2];
  const int t = threadIdx.x;
  if (t < B * 2) {
    const int b = t >> 1, j = t & 1;
    float h = 0.0f;
    for (int c = 0; c < C2; ++c)
      h += stats[OFF_POOL2 + b * C2 + c] * (1.0f / (float)HW) * w1[j * C2 + c];
    hid[b][j] = fmaxf(h, 0.0f);
  }
  __syncthreads();
  for (int i = t; i < B * C2; i += 64) {
    const int b = i / C2, c = i % C2;
    const float v = hid[b][0] * w2[c * 2 + 0] + hid[b][1] * w2[c * 2 + 1];
    stats[OFF_S2 + i] = 1.0f / (1.0f + expf(-v));
  }
}

// ---------------- single apply pass: x2 = leaky(bn2(raw)) * s2, in place ----------------
__global__ __launch_bounds__(256) void apply2_kernel(
    float* __restrict__ buf, const float* __restrict__ scale,
    const float* __restrict__ shift, const float* __restrict__ s2)
{
  const int c = blockIdx.y, b = blockIdx.z;
  const size_t base = ((size_t)(b * C2 + c)) * HW + blockIdx.x * 1024 + threadIdx.x * 4;
  const float sc = scale[c], sh = shift[c], s = s2[b * C2 + c];
  float4 v = *(const float4*)(buf + base);
  float r0 = fmaf(v.x, sc, sh); r0 = (r0 > 0.0f ? r0 : LEAK * r0) * s;
  float r1 = fmaf(v.y, sc, sh); r1 = (r1 > 0.0f ? r1 : LEAK * r1) * s;
  float r2 = fmaf(v.z, sc, sh); r2 = (r2 > 0.0f ? r2 : LEAK * r2) * s;
  float r3 = fmaf(v.w, sc, sh); r3 = (r3 > 0.0f ? r3 : LEAK * r3) * s;
  *(float4*)(buf + base) = make_float4(r0, r1, r2, r3);
}

// ---------------- final: out[b,j] = sum_o pooled[b,o]*fw[j,o] + fb[j] ----------------
// haar_idwt2(haar_dwt2(a)+haar_dwt2(b)) == a+b, so pooled = mean(x2 + reviewed).
__global__ void final_kernel(const float* __restrict__ stats,
                             const float* __restrict__ fw, const float* __restrict__ fb,
                             float* __restrict__ out)
{
  const int t = threadIdx.x;
  if (t < B * 2) {
    const int b = t >> 1, j = t & 1;
    float acc = fb[j];
    for (int o = 0; o < C2; ++o) {
      const float m = (stats[OFF_POOL2 + b * C2 + o] * stats[OFF_S2 + b * C2 + o]
                       + stats[OFF_REVSUM + b * C2 + o]) * (1.0f / (float)HW);
      acc = fmaf(m, fw[j * C2 + o], acc);
    }
    out[b * 2 + j] = acc;
  }
}

extern "C" void kernel_launch(void* const* d_in, const int* in_sizes, int n_in,
                              void* d_out, int out_size, void* d_ws, size_t ws_size,
                              hipStream_t stream) {
  const float* x        = (const float*)d_in[0];
  const float* conv1_w  = (const float*)d_in[1];
  const float* conv1_b  = (const float*)d_in[2];
  const float* bn1_g    = (const float*)d_in[3];
  const float* bn1_b    = (const float*)d_in[4];
  const float* se1_w1   = (const float*)d_in[5];
  const float* se1_w2   = (const float*)d_in[6];
  const float* conv2_w  = (const float*)d_in[7];
  const float* conv2_b  = (const float*)d_in[8];
  const float* bn2_g    = (const float*)d_in[9];
  const float* bn2_b    = (const float*)d_in[10];
  const float* se2_w1   = (const float*)d_in[11];
  const float* se2_w2   = (const float*)d_in[12];
  const float* review_w = (const float*)d_in[13];
  const float* review_b = (const float*)d_in[14];
  const float* final_w  = (const float*)d_in[15];
  const float* final_b  = (const float*)d_in[16];

  float* ws    = (float*)d_ws;
  float* x1buf = ws;                 // B*C1*HW floats (RAW conv1 output)
  float* stats = ws + X1_FLOATS;     // STATS_TOTAL floats
  float* out   = (float*)d_out;      // conv2 raw -> x2 in place; + 32 tail floats

  hipMemsetAsync(stats, 0, STATS_TOTAL * sizeof(float), stream);

  conv1_kernel<<<dim3(16, 16, B), 256, 0, stream>>>(
      x, conv1_w, conv1_b, x1buf, stats + OFF_BN1_SUM, stats + OFF_BN1_SQ);

  finalize_bn_kernel<<<1, 64, 0, stream>>>(stats, bn1_g, bn1_b, C1,
      OFF_BN1_SUM, OFF_BN1_SQ, OFF_BN1_SCALE, OFF_BN1_SHIFT);

  bnpool_kernel<<<dim3(64, C1, B), 256, 0, stream>>>(
      x1buf, stats + OFF_BN1_SCALE, stats + OFF_BN1_SHIFT, stats + OFF_POOL1, C1);

  se1_kernel<<<1, 64, 0, stream>>>(stats, se1_w1, se1_w2);

  conv2_kernel<<<dim3(16, 16, B), 256, 0, stream>>>(
      x1buf, conv2_w, conv2_b,
      stats + OFF_BN1_SCALE, stats + OFF_BN1_SHIFT, stats + OFF_S1,
      review_w, review_b,
      out, stats + OFF_BN2_SUM, stats + OFF_BN2_SQ, stats + OFF_REVSUM);

  finalize_bn_kernel<<<1, 64, 0, stream>>>(stats, bn2_g, bn2_b, C2,
      OFF_BN2_SUM, OFF_BN2_SQ, OFF_BN2_SCALE, OFF_BN2_SHIFT);

  bnpool_kernel<<<dim3(64, C2, B), 256, 0, stream>>>(
      out, stats + OFF_BN2_SCALE, stats + OFF_BN2_SHIFT, stats + OFF_POOL2, C2);

  se2_kernel<<<1, 64, 0, stream>>>(stats, se2_w1, se2_w2);

  apply2_kernel<<<dim3(64, C2, B), 256, 0, stream>>>(
      out, stats + OFF_BN2_SCALE, stats + OFF_BN2_SHIFT, stats + OFF_S2);

  final_kernel<<<1, 64, 0, stream>>>(stats, final_w, final_b, out + OUT_X2_FLOATS);
}

// Round 8
// 959.076 us; speedup vs baseline: 3.5007x; 3.5007x over previous
//
#include <hip/hip_runtime.h>
#include <math.h>

// ---------------- problem constants ----------------
#define B     16
#define C0    3
#define H0    510
#define W0    510
#define C1    18
#define C2    36
#define H     256
#define W     256
#define HW    65536          // 256*256
#define NSTAT 1048576        // B*HW, BN reduction count
#define EPS   1e-5f
#define LEAK  0.1f

// ws float offsets
#define X1_FLOATS   18874368   // B*C1*HW
#define OFF_BN1_SUM   0
#define OFF_BN1_SQ    18
#define OFF_BN1_SCALE 36
#define OFF_BN1_SHIFT 54
#define OFF_POOL1     72      // 16*18 = 288
#define OFF_S1        360     // 288
#define OFF_BN2_SUM   648
#define OFF_BN2_SQ    684
#define OFF_BN2_SCALE 720
#define OFF_BN2_SHIFT 756
#define OFF_POOL2     792     // 16*36 = 576
#define OFF_S2        1368    // 576
#define OFF_REVSUM    1944    // 576
#define STATS_TOTAL   2520

#define OUT_X2_FLOATS 37748736  // B*C2*HW

__device__ inline float wave_reduce_sum(float v) {
  #pragma unroll
  for (int off = 32; off > 0; off >>= 1) v += __shfl_down(v, off, 64);
  return v;
}

template<int NCH>
__device__ inline void block_stats(const float* acc, float* gsum, float* gsq) {
  __shared__ float smem_s[4][NCH];
  __shared__ float smem_q[4][NCH];
  const int tid = threadIdx.x, wave = tid >> 6, lane = tid & 63;
  #pragma unroll
  for (int o = 0; o < NCH; ++o) {
    float s = wave_reduce_sum(acc[o]);
    float q = wave_reduce_sum(acc[o] * acc[o]);
    if (lane == 0) { smem_s[wave][o] = s; smem_q[wave][o] = q; }
  }
  __syncthreads();
  if (tid < NCH) {
    atomicAdd(&gsum[tid], smem_s[0][tid] + smem_s[1][tid] + smem_s[2][tid] + smem_s[3][tid]);
    atomicAdd(&gsq[tid],  smem_q[0][tid] + smem_q[1][tid] + smem_q[2][tid] + smem_q[3][tid]);
  }
}

// ---------------- conv1: 3->18, 4x4, stride 2, pad 2, fused BN1 stats ----------------
// Writes RAW conv output (pre-BN). BN1 is applied on the fly by all consumers.
// Taps ride vmcnt (global), weights ride lgkmcnt (SMEM) -- already separated.
__global__ __launch_bounds__(256) void conv1_kernel(
    const float* __restrict__ x, const float* __restrict__ w,
    const float* __restrict__ bias, float* __restrict__ out,
    float* __restrict__ gsum, float* __restrict__ gsq)
{
  const int b = blockIdx.z;
  const int tid = threadIdx.x;
  const int ly = tid >> 4, lx = tid & 15;
  const int oy = blockIdx.y * 16 + ly;
  const int ox = blockIdx.x * 16 + lx;

  float acc[C1];
  #pragma unroll
  for (int o = 0; o < C1; ++o) acc[o] = bias[o];

  const float* xb = x + (size_t)b * C0 * H0 * W0;
  #pragma unroll
  for (int c = 0; c < C0; ++c) {
    float iv[16];
    #pragma unroll
    for (int ky = 0; ky < 4; ++ky) {
      const int iy = oy * 2 - 2 + ky;
      #pragma unroll
      for (int kx = 0; kx < 4; ++kx) {
        const int ix = ox * 2 - 2 + kx;
        const bool ok = (iy >= 0) && (iy < H0) && (ix >= 0) && (ix < W0);
        iv[ky * 4 + kx] = ok ? xb[c * (H0 * W0) + iy * W0 + ix] : 0.0f;
      }
    }
    #pragma unroll
    for (int o = 0; o < C1; ++o) {
      float a = acc[o];
      #pragma unroll
      for (int t = 0; t < 16; ++t) a = fmaf(iv[t], w[o * 48 + c * 16 + t], a);
      acc[o] = a;
    }
  }

  float* ob = out + ((size_t)b * C1) * HW + oy * W + ox;
  #pragma unroll
  for (int o = 0; o < C1; ++o) ob[(size_t)o * HW] = acc[o];

  block_stats<C1>(acc, gsum, gsq);
}

// ---------------- BN finalize (both layers) ----------------
__global__ void finalize_bn_kernel(float* __restrict__ stats,
                                   const float* __restrict__ g, const float* __restrict__ be,
                                   int nch, int sum_off, int sq_off, int scale_off, int shift_off)
{
  const int t = threadIdx.x;
  if (t < nch) {
    const float inv_n = 1.0f / (float)NSTAT;
    float mean = stats[sum_off + t] * inv_n;
    float var  = stats[sq_off + t] * inv_n - mean * mean;
    float sc   = g[t] * rsqrtf(var + EPS);
    stats[scale_off + t] = sc;
    stats[shift_off + t] = be[t] - mean * sc;
  }
}

// ---------------- BN+leaky pool (compute-only, no write-back) ----------------
// pool[b,c] += sum over pixels of leaky_relu(raw*sc + sh)
__global__ __launch_bounds__(256) void bnpool_kernel(
    const float* __restrict__ buf, const float* __restrict__ scale,
    const float* __restrict__ shift, float* __restrict__ pool, int nch)
{
  const int c = blockIdx.y, b = blockIdx.z;
  const int tid = threadIdx.x;
  const size_t base = ((size_t)(b * nch + c)) * HW + blockIdx.x * 1024 + tid * 4;
  const float sc = scale[c], sh = shift[c];
  float4 v = *(const float4*)(buf + base);
  float r0 = fmaf(v.x, sc, sh); r0 = r0 > 0.0f ? r0 : LEAK * r0;
  float r1 = fmaf(v.y, sc, sh); r1 = r1 > 0.0f ? r1 : LEAK * r1;
  float r2 = fmaf(v.z, sc, sh); r2 = r2 > 0.0f ? r2 : LEAK * r2;
  float r3 = fmaf(v.w, sc, sh); r3 = r3 > 0.0f ? r3 : LEAK * r3;

  float s = wave_reduce_sum(r0 + r1 + r2 + r3);
  __shared__ float smem[4];
  const int wave = tid >> 6, lane = tid & 63;
  if (lane == 0) smem[wave] = s;
  __syncthreads();
  if (tid == 0) atomicAdd(&pool[b * nch + c], smem[0] + smem[1] + smem[2] + smem[3]);
}

// ---------------- SE1: hidden dim 1 ----------------
__global__ void se1_kernel(float* __restrict__ stats,
                           const float* __restrict__ w1, const float* __restrict__ w2)
{
  __shared__ float hid[B];
  const int t = threadIdx.x;
  if (t < B) {
    float h = 0.0f;
    for (int c = 0; c < C1; ++c)
      h += stats[OFF_POOL1 + t * C1 + c] * (1.0f / (float)HW) * w1[c];
    hid[t] = fmaxf(h, 0.0f);
  }
  __syncthreads();
  for (int i = t; i < B * C1; i += 64) {
    const int b = i / C1, c = i % C1;
    const float v = hid[b] * w2[c];
    stats[OFF_S1 + i] = 1.0f / (1.0f + expf(-v));
  }
}

// ---------------- conv2: 18->36, 3x3, pad 1 ----------------
// 1 px/thread, 16x16 tile, 2 passes of 18 output channels.
// KEY FIX (R5 stall diagnosis): SMEM returns out-of-order, so scalar weight
// loads in the inner loop force s_waitcnt lgkmcnt(0), draining all pending
// LDS tap reads. Weights are therefore staged in LDS per pass (15.5 KB,
// layout [j][c][12] so each (c,j) is 3 aligned ds_read_b128 broadcasts);
// DS is in-order -> fine-grained lgkmcnt, taps and weights pipeline.
// (R7 showed the VMEM route thrashes L2: FETCH 139MB->2.1GB. Reverted.)
__global__ __launch_bounds__(256, 4) void conv2_kernel(
    const float* __restrict__ x1raw, const float* __restrict__ w,
    const float* __restrict__ bias, const float* __restrict__ sc1,
    const float* __restrict__ sh1, const float* __restrict__ s1,
    const float* __restrict__ rw, const float* __restrict__ rb,
    float* __restrict__ out, float* __restrict__ gsum, float* __restrict__ gsq,
    float* __restrict__ revsum)
{
  __shared__ float  in_lds[C1 * 18 * 18];   // 23328 B, [c][iy][ix], BN1-applied, pre-s1
  __shared__ float4 w_lds4[18 * 18 * 3];    // 15552 B, [j][c][3xfloat4] (9 taps + 3 pad)
  __shared__ float  red_s[4][18];
  __shared__ float  red_q[4][18];
  __shared__ float  red_r[4][18];

  const int b = blockIdx.z;
  const int ty0 = blockIdx.y * 16, tx0 = blockIdx.x * 16;
  const int tid = threadIdx.x;
  float* w_lds = (float*)w_lds4;

  const float* xb = x1raw + (size_t)b * C1 * HW;
  for (int i = tid; i < C1 * 324; i += 256) {
    const int c = i / 324;
    const int rem = i - c * 324;
    const int r = rem / 18;
    const int col = rem - r * 18;
    const int gy = ty0 - 1 + r;
    const int gx = tx0 - 1 + col;
    float v = 0.0f;
    if (gy >= 0 && gy < H && gx >= 0 && gx < W) {
      v = fmaf(xb[c * HW + gy * W + gx], sc1[c], sh1[c]);
      v = v > 0.0f ? v : LEAK * v;           // this IS x1 (post-BN, pre-SE)
    }
    in_lds[i] = v;
  }
  // stage pass-0 weights: w_lds[(j*18+c)*12 + t] = w[(j)*162 + c*9 + t]
  for (int i = tid; i < 18 * 162; i += 256) {
    const int j = i / 162, rem = i - j * 162;
    const int c = rem / 9, t = rem - c * 9;
    w_lds[(j * 18 + c) * 12 + t] = w[(size_t)j * 162 + rem];
  }
  __syncthreads();

  const int ly = tid >> 4, lx = tid & 15;
  const int wave = tid >> 6, lane = tid & 63;

  // preload s1 so no scalar load survives inside the c-loop
  const float* s1b = s1 + b * C1;
  float s1r[C1];
  #pragma unroll
  for (int c = 0; c < C1; ++c) s1r[c] = s1b[c];

  #pragma unroll 1
  for (int p = 0; p < 2; ++p) {            // channels [18p, 18p+18)
    const int ob18 = p * 18;
    float acc[18], cent[C1];
    #pragma unroll
    for (int j = 0; j < 18; ++j) acc[j] = bias[ob18 + j];

    for (int c = 0; c < C1; ++c) {
      float iv[9];
      #pragma unroll
      for (int ky = 0; ky < 3; ++ky)
        #pragma unroll
        for (int kx = 0; kx < 3; ++kx)
          iv[ky * 3 + kx] = in_lds[c * 324 + (ly + ky) * 18 + (lx + kx)];

      cent[c] = iv[4];                     // center, pre-s1 (= x1) for review
      const float s1c = s1r[c];
      #pragma unroll
      for (int t = 0; t < 9; ++t) iv[t] *= s1c;

      #pragma unroll
      for (int j = 0; j < 18; ++j) {
        const float4 w0 = w_lds4[(j * 18 + c) * 3 + 0];
        const float4 w1 = w_lds4[(j * 18 + c) * 3 + 1];
        const float4 w2 = w_lds4[(j * 18 + c) * 3 + 2];
        float a = acc[j];
        a = fmaf(iv[0], w0.x, a); a = fmaf(iv[1], w0.y, a); a = fmaf(iv[2], w0.z, a);
        a = fmaf(iv[3], w0.w, a); a = fmaf(iv[4], w1.x, a); a = fmaf(iv[5], w1.y, a);
        a = fmaf(iv[6], w1.z, a); a = fmaf(iv[7], w1.w, a); a = fmaf(iv[8], w2.x, a);
        acc[j] = a;
      }
    }

    // review 1x1 epilogue: contiguous rw rows (SMEM ok here), centers in regs
    float racc[18];
    #pragma unroll
    for (int j = 0; j < 18; ++j) {
      const float* rr = rw + (size_t)(ob18 + j) * C1;
      float r = rb[ob18 + j];
      #pragma unroll
      for (int c = 0; c < C1; ++c) r = fmaf(cent[c], rr[c], r);
      racc[j] = r;
    }

    // store this pass's 18 channels (coalesced across lx)
    float* ob = out + ((size_t)(b * C2 + ob18)) * HW + (ty0 + ly) * W + tx0 + lx;
    #pragma unroll
    for (int j = 0; j < 18; ++j) ob[(size_t)j * HW] = acc[j];

    // BN2 stats + review sums for these 18 channels
    __syncthreads();   // (A) w_lds/red reads of this pass complete
    #pragma unroll
    for (int j = 0; j < 18; ++j) {
      float s  = wave_reduce_sum(acc[j]);
      float qq = wave_reduce_sum(acc[j] * acc[j]);
      float rs = wave_reduce_sum(fmaxf(racc[j], 0.0f));
      if (lane == 0) { red_s[wave][j] = s; red_q[wave][j] = qq; red_r[wave][j] = rs; }
    }
    __syncthreads();   // (B) red arrays complete
    if (tid < 18) {
      atomicAdd(&gsum[ob18 + tid], red_s[0][tid] + red_s[1][tid] + red_s[2][tid] + red_s[3][tid]);
      atomicAdd(&gsq[ob18 + tid],  red_q[0][tid] + red_q[1][tid] + red_q[2][tid] + red_q[3][tid]);
      atomicAdd(&revsum[b * C2 + ob18 + tid],
                red_r[0][tid] + red_r[1][tid] + red_r[2][tid] + red_r[3][tid]);
    }
    if (p == 0) {
      // restage weights for pass 1 (safe: reads finished at (A))
      for (int i = tid; i < 18 * 162; i += 256) {
        const int j = i / 162, rem = i - j * 162;
        const int c = rem / 9, t = rem - c * 9;
        w_lds[(j * 18 + c) * 12 + t] = w[(size_t)(18 + j) * 162 + rem];
      }
      __syncthreads();  // (C) pass-1 weights visible
    }
  }
}

// ---------------- SE2: hidden dim 2 ----------------
__global__ void se2_kernel(float* __restrict__ stats,
                           const float* __restrict__ w1, const float* __restrict__ w2)
{
  __shared__ float hid[B][2];
  const int t = threadIdx.x;
  if (t < B * 2) {
    const int b = t >> 1, j = t & 1;
    float h = 0.0f;
    for (int c = 0; c < C2; ++c)
      h += stats[OFF_POOL2 + b * C2 + c] * (1.0f / (float)HW) * w1[j * C2 + c];
    hid[b][j] = fmaxf(h, 0.0f);
  }
  __syncthreads();
  for (int i = t; i < B * C2; i += 64) {
    const int b = i / C2, c = i % C2;
    const float v = hid[b][0] * w2[c * 2 + 0] + hid[b][1] * w2[c * 2 + 1];
    stats[OFF_S2 + i] = 1.0f / (1.0f + expf(-v));
  }
}

// ---------------- single apply pass: x2 = leaky(bn2(raw)) * s2, in place ----------------
__global__ __launch_bounds__(256) void apply2_kernel(
    float* __restrict__ buf, const float* __restrict__ scale,
    const float* __restrict__ shift, const float* __restrict__ s2)
{
  const int c = blockIdx.y, b = blockIdx.z;
  const size_t base = ((size_t)(b * C2 + c)) * HW + blockIdx.x * 1024 + threadIdx.x * 4;
  const float sc = scale[c], sh = shift[c], s = s2[b * C2 + c];
  float4 v = *(const float4*)(buf + base);
  float r0 = fmaf(v.x, sc, sh); r0 = (r0 > 0.0f ? r0 : LEAK * r0) * s;
  float r1 = fmaf(v.y, sc, sh); r1 = (r1 > 0.0f ? r1 : LEAK * r1) * s;
  float r2 = fmaf(v.z, sc, sh); r2 = (r2 > 0.0f ? r2 : LEAK * r2) * s;
  float r3 = fmaf(v.w, sc, sh); r3 = (r3 > 0.0f ? r3 : LEAK * r3) * s;
  *(float4*)(buf + base) = make_float4(r0, r1, r2, r3);
}

// ---------------- final: out[b,j] = sum_o pooled[b,o]*fw[j,o] + fb[j] ----------------
// haar_idwt2(haar_dwt2(a)+haar_dwt2(b)) == a+b, so pooled = mean(x2 + reviewed).
__global__ void final_kernel(const float* __restrict__ stats,
                             const float* __restrict__ fw, const float* __restrict__ fb,
                             float* __restrict__ out)
{
  const int t = threadIdx.x;
  if (t < B * 2) {
    const int b = t >> 1, j = t & 1;
    float acc = fb[j];
    for (int o = 0; o < C2; ++o) {
      const float m = (stats[OFF_POOL2 + b * C2 + o] * stats[OFF_S2 + b * C2 + o]
                       + stats[OFF_REVSUM + b * C2 + o]) * (1.0f / (float)HW);
      acc = fmaf(m, fw[j * C2 + o], acc);
    }
    out[b * 2 + j] = acc;
  }
}

extern "C" void kernel_launch(void* const* d_in, const int* in_sizes, int n_in,
                              void* d_out, int out_size, void* d_ws, size_t ws_size,
                              hipStream_t stream) {
  const float* x        = (const float*)d_in[0];
  const float* conv1_w  = (const float*)d_in[1];
  const float* conv1_b  = (const float*)d_in[2];
  const float* bn1_g    = (const float*)d_in[3];
  const float* bn1_b    = (const float*)d_in[4];
  const float* se1_w1   = (const float*)d_in[5];
  const float* se1_w2   = (const float*)d_in[6];
  const float* conv2_w  = (const float*)d_in[7];
  const float* conv2_b  = (const float*)d_in[8];
  const float* bn2_g    = (const float*)d_in[9];
  const float* bn2_b    = (const float*)d_in[10];
  const float* se2_w1   = (const float*)d_in[11];
  const float* se2_w2   = (const float*)d_in[12];
  const float* review_w = (const float*)d_in[13];
  const float* review_b = (const float*)d_in[14];
  const float* final_w  = (const float*)d_in[15];
  const float* final_b  = (const float*)d_in[16];

  float* ws    = (float*)d_ws;
  float* x1buf = ws;                 // B*C1*HW floats (RAW conv1 output)
  float* stats = ws + X1_FLOATS;     // STATS_TOTAL floats
  float* out   = (float*)d_out;      // conv2 raw -> x2 in place; + 32 tail floats

  hipMemsetAsync(stats, 0, STATS_TOTAL * sizeof(float), stream);

  conv1_kernel<<<dim3(16, 16, B), 256, 0, stream>>>(
      x, conv1_w, conv1_b, x1buf, stats + OFF_BN1_SUM, stats + OFF_BN1_SQ);

  finalize_bn_kernel<<<1, 64, 0, stream>>>(stats, bn1_g, bn1_b, C1,
      OFF_BN1_SUM, OFF_BN1_SQ, OFF_BN1_SCALE, OFF_BN1_SHIFT);

  bnpool_kernel<<<dim3(64, C1, B), 256, 0, stream>>>(
      x1buf, stats + OFF_BN1_SCALE, stats + OFF_BN1_SHIFT, stats + OFF_POOL1, C1);

  se1_kernel<<<1, 64, 0, stream>>>(stats, se1_w1, se1_w2);

  conv2_kernel<<<dim3(16, 16, B), 256, 0, stream>>>(
      x1buf, conv2_w, conv2_b,
      stats + OFF_BN1_SCALE, stats + OFF_BN1_SHIFT, stats + OFF_S1,
      review_w, review_b,
      out, stats + OFF_BN2_SUM, stats + OFF_BN2_SQ, stats + OFF_REVSUM);

  finalize_bn_kernel<<<1, 64, 0, stream>>>(stats, bn2_g, bn2_b, C2,
      OFF_BN2_SUM, OFF_BN2_SQ, OFF_BN2_SCALE, OFF_BN2_SHIFT);

  bnpool_kernel<<<dim3(64, C2, B), 256, 0, stream>>>(
      out, stats + OFF_BN2_SCALE, stats + OFF_BN2_SHIFT, stats + OFF_POOL2, C2);

  se2_kernel<<<1, 64, 0, stream>>>(stats, se2_w1, se2_w2);

  apply2_kernel<<<dim3(64, C2, B), 256, 0, stream>>>(
      out, stats + OFF_BN2_SCALE, stats + OFF_BN2_SHIFT, stats + OFF_S2);

  final_kernel<<<1, 64, 0, stream>>>(stats, final_w, final_b, out + OUT_X2_FLOATS);
}

// Round 9
// 806.830 us; speedup vs baseline: 4.1613x; 1.1887x over previous
//
#include <hip/hip_runtime.h>
#include <math.h>

// ---------------- problem constants ----------------
#define B     16
#define C0    3
#define H0    510
#define W0    510
#define C1    18
#define C2    36
#define H     256
#define W     256
#define HW    65536          // 256*256
#define NSTAT 1048576        // B*HW, BN reduction count
#define EPS   1e-5f
#define LEAK  0.1f

// ws float offsets
#define X1_FLOATS   18874368   // B*C1*HW
#define OFF_BN1_SUM   0
#define OFF_BN1_SQ    18
#define OFF_POOL1     72      // 16*18 = 288
#define OFF_S1        360     // 288
#define OFF_BN2_SUM   648
#define OFF_BN2_SQ    684
#define OFF_POOL2     792     // 16*36 = 576
#define OFF_S2        1368    // 576
#define OFF_REVSUM    1944    // 576
#define STATS_TOTAL   2520

#define OUT_X2_FLOATS 37748736  // B*C2*HW

__device__ inline float wave_reduce_sum(float v) {
  #pragma unroll
  for (int off = 32; off > 0; off >>= 1) v += __shfl_down(v, off, 64);
  return v;
}

template<int NCH>
__device__ inline void block_stats(const float* acc, float* gsum, float* gsq) {
  __shared__ float smem_s[4][NCH];
  __shared__ float smem_q[4][NCH];
  const int tid = threadIdx.x, wave = tid >> 6, lane = tid & 63;
  #pragma unroll
  for (int o = 0; o < NCH; ++o) {
    float s = wave_reduce_sum(acc[o]);
    float q = wave_reduce_sum(acc[o] * acc[o]);
    if (lane == 0) { smem_s[wave][o] = s; smem_q[wave][o] = q; }
  }
  __syncthreads();
  if (tid < NCH) {
    atomicAdd(&gsum[tid], smem_s[0][tid] + smem_s[1][tid] + smem_s[2][tid] + smem_s[3][tid]);
    atomicAdd(&gsq[tid],  smem_q[0][tid] + smem_q[1][tid] + smem_q[2][tid] + smem_q[3][tid]);
  }
}

// ---------------- conv1: 3->18, 4x4, stride 2, pad 2, fused BN1 stats ----------------
// Writes RAW conv output (pre-BN). Interior blocks (bx,by in [1,14]) skip all
// boundary cmp/cndmask (77% of blocks, ~190 VALU ops saved per thread).
__global__ __launch_bounds__(256) void conv1_kernel(
    const float* __restrict__ x, const float* __restrict__ w,
    const float* __restrict__ bias, float* __restrict__ out,
    float* __restrict__ gsum, float* __restrict__ gsq)
{
  const int b = blockIdx.z;
  const int tid = threadIdx.x;
  const int ly = tid >> 4, lx = tid & 15;
  const int oy = blockIdx.y * 16 + ly;
  const int ox = blockIdx.x * 16 + lx;

  float acc[C1];
  #pragma unroll
  for (int o = 0; o < C1; ++o) acc[o] = bias[o];

  const float* xb = x + (size_t)b * C0 * H0 * W0;
  const bool interior = (blockIdx.x >= 1) && (blockIdx.x <= 14) &&
                        (blockIdx.y >= 1) && (blockIdx.y <= 14);

  if (interior) {
    const float* xp = xb + (oy * 2 - 2) * W0 + (ox * 2 - 2);
    #pragma unroll
    for (int c = 0; c < C0; ++c) {
      float iv[16];
      #pragma unroll
      for (int ky = 0; ky < 4; ++ky)
        #pragma unroll
        for (int kx = 0; kx < 4; ++kx)
          iv[ky * 4 + kx] = xp[c * (H0 * W0) + ky * W0 + kx];
      #pragma unroll
      for (int o = 0; o < C1; ++o) {
        float a = acc[o];
        #pragma unroll
        for (int t = 0; t < 16; ++t) a = fmaf(iv[t], w[o * 48 + c * 16 + t], a);
        acc[o] = a;
      }
    }
  } else {
    #pragma unroll
    for (int c = 0; c < C0; ++c) {
      float iv[16];
      #pragma unroll
      for (int ky = 0; ky < 4; ++ky) {
        const int iy = oy * 2 - 2 + ky;
        #pragma unroll
        for (int kx = 0; kx < 4; ++kx) {
          const int ix = ox * 2 - 2 + kx;
          const bool ok = (iy >= 0) && (iy < H0) && (ix >= 0) && (ix < W0);
          iv[ky * 4 + kx] = ok ? xb[c * (H0 * W0) + iy * W0 + ix] : 0.0f;
        }
      }
      #pragma unroll
      for (int o = 0; o < C1; ++o) {
        float a = acc[o];
        #pragma unroll
        for (int t = 0; t < 16; ++t) a = fmaf(iv[t], w[o * 48 + c * 16 + t], a);
        acc[o] = a;
      }
    }
  }

  float* ob = out + ((size_t)b * C1) * HW + oy * W + ox;
  #pragma unroll
  for (int o = 0; o < C1; ++o) ob[(size_t)o * HW] = acc[o];

  block_stats<C1>(acc, gsum, gsq);
}

// ---------------- BN+leaky pool (compute-only), BN finalize inlined ----------------
// pool[b,c] += sum over pixels of leaky_relu(raw*sc + sh); sc/sh computed from
// raw gsum/gsq per block (wave-uniform, ~10 ops). 8 blocks/plane, 32 floats/thread.
__global__ __launch_bounds__(256) void bnpool_kernel(
    const float* __restrict__ buf, const float* __restrict__ stats,
    int sum_off, int sq_off,
    const float* __restrict__ g, const float* __restrict__ be,
    float* __restrict__ pool, int nch)
{
  const int c = blockIdx.y, b = blockIdx.z;
  const int tid = threadIdx.x;
  const float inv_n = 1.0f / (float)NSTAT;
  const float mean = stats[sum_off + c] * inv_n;
  const float var  = stats[sq_off + c] * inv_n - mean * mean;
  const float sc   = g[c] * rsqrtf(var + EPS);
  const float sh   = be[c] - mean * sc;

  const float* p = buf + ((size_t)(b * nch + c)) * HW + blockIdx.x * 8192 + tid * 4;
  float acc = 0.0f;
  #pragma unroll
  for (int k = 0; k < 8; ++k) {
    float4 v = *(const float4*)(p + k * 1024);
    float r0 = fmaf(v.x, sc, sh); r0 = r0 > 0.0f ? r0 : LEAK * r0;
    float r1 = fmaf(v.y, sc, sh); r1 = r1 > 0.0f ? r1 : LEAK * r1;
    float r2 = fmaf(v.z, sc, sh); r2 = r2 > 0.0f ? r2 : LEAK * r2;
    float r3 = fmaf(v.w, sc, sh); r3 = r3 > 0.0f ? r3 : LEAK * r3;
    acc += (r0 + r1) + (r2 + r3);
  }

  float s = wave_reduce_sum(acc);
  __shared__ float smem[4];
  const int wave = tid >> 6, lane = tid & 63;
  if (lane == 0) smem[wave] = s;
  __syncthreads();
  if (tid == 0) atomicAdd(&pool[b * nch + c], smem[0] + smem[1] + smem[2] + smem[3]);
}

// ---------------- SE1: hidden dim 1 ----------------
__global__ void se1_kernel(float* __restrict__ stats,
                           const float* __restrict__ w1, const float* __restrict__ w2)
{
  __shared__ float hid[B];
  const int t = threadIdx.x;
  if (t < B) {
    float h = 0.0f;
    for (int c = 0; c < C1; ++c)
      h += stats[OFF_POOL1 + t * C1 + c] * (1.0f / (float)HW) * w1[c];
    hid[t] = fmaxf(h, 0.0f);
  }
  __syncthreads();
  for (int i = t; i < B * C1; i += 64) {
    const int b = i / C1, c = i % C1;
    const float v = hid[b] * w2[c];
    stats[OFF_S1 + i] = 1.0f / (1.0f + expf(-v));
  }
}

// ---------------- conv2: 18->36, 3x3, pad 1 (exact R5 structure) ----------------
// 1 px/thread, 16x16 tile, 2 passes of 18 output channels, s_load weights,
// launch_bounds(256,6) for the ~84-VGPR budget (R5: 392 us, proven fastest).
// BN1 finalize inlined into LDS during staging (replaces finalize launch).
__global__ __launch_bounds__(256, 6) void conv2_kernel(
    const float* __restrict__ x1raw, const float* __restrict__ w,
    const float* __restrict__ bias, const float* __restrict__ stats,
    const float* __restrict__ bn1_g, const float* __restrict__ bn1_b,
    const float* __restrict__ s1,
    const float* __restrict__ rw, const float* __restrict__ rb,
    float* __restrict__ out, float* __restrict__ gsum, float* __restrict__ gsq,
    float* __restrict__ revsum)
{
  __shared__ float in_lds[C1 * 18 * 18];   // [c][iy][ix], BN1-applied, pre-s1
  __shared__ float bn1sc[C1], bn1sh[C1];
  __shared__ float red_s[4][18];
  __shared__ float red_q[4][18];
  __shared__ float red_r[4][18];

  const int b = blockIdx.z;
  const int ty0 = blockIdx.y * 16, tx0 = blockIdx.x * 16;
  const int tid = threadIdx.x;

  if (tid < C1) {
    const float inv_n = 1.0f / (float)NSTAT;
    const float mean = stats[OFF_BN1_SUM + tid] * inv_n;
    const float var  = stats[OFF_BN1_SQ + tid] * inv_n - mean * mean;
    const float sc   = bn1_g[tid] * rsqrtf(var + EPS);
    bn1sc[tid] = sc;
    bn1sh[tid] = bn1_b[tid] - mean * sc;
  }
  __syncthreads();

  const float* xb = x1raw + (size_t)b * C1 * HW;
  for (int i = tid; i < C1 * 324; i += 256) {
    const int c = i / 324;
    const int rem = i - c * 324;
    const int r = rem / 18;
    const int col = rem - r * 18;
    const int gy = ty0 - 1 + r;
    const int gx = tx0 - 1 + col;
    float v = 0.0f;
    if (gy >= 0 && gy < H && gx >= 0 && gx < W) {
      v = fmaf(xb[c * HW + gy * W + gx], bn1sc[c], bn1sh[c]);
      v = v > 0.0f ? v : LEAK * v;           // this IS x1 (post-BN, pre-SE)
    }
    in_lds[i] = v;
  }
  __syncthreads();

  const int ly = tid >> 4, lx = tid & 15;
  const int wave = tid >> 6, lane = tid & 63;
  const float* s1b = s1 + b * C1;

  #pragma unroll 1
  for (int p = 0; p < 2; ++p) {            // channels [18p, 18p+18)
    const int ob18 = p * 18;
    float acc[18], racc[18], cent[C1];
    #pragma unroll
    for (int j = 0; j < 18; ++j) { acc[j] = bias[ob18 + j]; racc[j] = rb[ob18 + j]; }

    for (int c = 0; c < C1; ++c) {
      float iv[9];
      #pragma unroll
      for (int ky = 0; ky < 3; ++ky)
        #pragma unroll
        for (int kx = 0; kx < 3; ++kx)
          iv[ky * 3 + kx] = in_lds[c * 324 + (ly + ky) * 18 + (lx + kx)];

      cent[c] = iv[4];                     // center, pre-s1 (= x1) for review
      const float s1c = s1b[c];
      #pragma unroll
      for (int t = 0; t < 9; ++t) iv[t] *= s1c;

      const float* wc = w + (size_t)ob18 * 162 + c * 9;   // block-uniform
      #pragma unroll
      for (int j = 0; j < 18; ++j) {
        #pragma unroll
        for (int t = 0; t < 9; ++t)
          acc[j] = fmaf(iv[t], wc[j * 162 + t], acc[j]);
      }
    }

    // review 1x1 epilogue: contiguous rw rows, centers in regs
    #pragma unroll
    for (int j = 0; j < 18; ++j) {
      const float* rr = rw + (size_t)(ob18 + j) * C1;
      float r = racc[j];
      #pragma unroll
      for (int c = 0; c < C1; ++c) r = fmaf(cent[c], rr[c], r);
      racc[j] = r;
    }

    // store this pass's 18 channels (coalesced across lx)
    float* ob = out + ((size_t)(b * C2 + ob18)) * HW + (ty0 + ly) * W + tx0 + lx;
    #pragma unroll
    for (int j = 0; j < 18; ++j) ob[(size_t)j * HW] = acc[j];

    // BN2 stats + review sums for these 18 channels
    __syncthreads();   // guard smem reuse across passes
    #pragma unroll
    for (int j = 0; j < 18; ++j) {
      float s  = wave_reduce_sum(acc[j]);
      float qq = wave_reduce_sum(acc[j] * acc[j]);
      float rs = wave_reduce_sum(fmaxf(racc[j], 0.0f));
      if (lane == 0) { red_s[wave][j] = s; red_q[wave][j] = qq; red_r[wave][j] = rs; }
    }
    __syncthreads();
    if (tid < 18) {
      atomicAdd(&gsum[ob18 + tid], red_s[0][tid] + red_s[1][tid] + red_s[2][tid] + red_s[3][tid]);
      atomicAdd(&gsq[ob18 + tid],  red_q[0][tid] + red_q[1][tid] + red_q[2][tid] + red_q[3][tid]);
      atomicAdd(&revsum[b * C2 + ob18 + tid],
                red_r[0][tid] + red_r[1][tid] + red_r[2][tid] + red_r[3][tid]);
    }
  }
}

// ---------------- SE2: hidden dim 2 ----------------
__global__ void se2_kernel(float* __restrict__ stats,
                           const float* __restrict__ w1, const float* __restrict__ w2)
{
  __shared__ float hid[B][2];
  const int t = threadIdx.x;
  if (t < B * 2) {
    const int b = t >> 1, j = t & 1;
    float h = 0.0f;
    for (int c = 0; c < C2; ++c)
      h += stats[OFF_POOL2 + b * C2 + c] * (1.0f / (float)HW) * w1[j * C2 + c];
    hid[b][j] = fmaxf(h, 0.0f);
  }
  __syncthreads();
  for (int i = t; i < B * C2; i += 64) {
    const int b = i / C2, c = i % C2;
    const float v = hid[b][0] * w2[c * 2 + 0] + hid[b][1] * w2[c * 2 + 1];
    stats[OFF_S2 + i] = 1.0f / (1.0f + expf(-v));
  }
}

// ---------------- apply pass: x2 = leaky(bn2(raw)) * s2, in place; fin inlined ----------------
__global__ __launch_bounds__(256) void apply2_kernel(
    float* __restrict__ buf, const float* __restrict__ stats,
    const float* __restrict__ g, const float* __restrict__ be,
    const float* __restrict__ s2)
{
  const int c = blockIdx.y, b = blockIdx.z;
  const int tid = threadIdx.x;
  const float inv_n = 1.0f / (float)NSTAT;
  const float mean = stats[OFF_BN2_SUM + c] * inv_n;
  const float var  = stats[OFF_BN2_SQ + c] * inv_n - mean * mean;
  const float sc   = g[c] * rsqrtf(var + EPS);
  const float sh   = be[c] - mean * sc;
  const float s    = s2[b * C2 + c];

  float* p = buf + ((size_t)(b * C2 + c)) * HW + blockIdx.x * 4096 + tid * 4;
  #pragma unroll
  for (int k = 0; k < 4; ++k) {
    float4 v = *(const float4*)(p + k * 1024);
    float r0 = fmaf(v.x, sc, sh); r0 = (r0 > 0.0f ? r0 : LEAK * r0) * s;
    float r1 = fmaf(v.y, sc, sh); r1 = (r1 > 0.0f ? r1 : LEAK * r1) * s;
    float r2 = fmaf(v.z, sc, sh); r2 = (r2 > 0.0f ? r2 : LEAK * r2) * s;
    float r3 = fmaf(v.w, sc, sh); r3 = (r3 > 0.0f ? r3 : LEAK * r3) * s;
    *(float4*)(p + k * 1024) = make_float4(r0, r1, r2, r3);
  }
}

// ---------------- final: out[b,j] = sum_o pooled[b,o]*fw[j,o] + fb[j] ----------------
// haar_idwt2(haar_dwt2(a)+haar_dwt2(b)) == a+b, so pooled = mean(x2 + reviewed).
__global__ void final_kernel(const float* __restrict__ stats,
                             const float* __restrict__ fw, const float* __restrict__ fb,
                             float* __restrict__ out)
{
  const int t = threadIdx.x;
  if (t < B * 2) {
    const int b = t >> 1, j = t & 1;
    float acc = fb[j];
    for (int o = 0; o < C2; ++o) {
      const float m = (stats[OFF_POOL2 + b * C2 + o] * stats[OFF_S2 + b * C2 + o]
                       + stats[OFF_REVSUM + b * C2 + o]) * (1.0f / (float)HW);
      acc = fmaf(m, fw[j * C2 + o], acc);
    }
    out[b * 2 + j] = acc;
  }
}

extern "C" void kernel_launch(void* const* d_in, const int* in_sizes, int n_in,
                              void* d_out, int out_size, void* d_ws, size_t ws_size,
                              hipStream_t stream) {
  const float* x        = (const float*)d_in[0];
  const float* conv1_w  = (const float*)d_in[1];
  const float* conv1_b  = (const float*)d_in[2];
  const float* bn1_g    = (const float*)d_in[3];
  const float* bn1_b    = (const float*)d_in[4];
  const float* se1_w1   = (const float*)d_in[5];
  const float* se1_w2   = (const float*)d_in[6];
  const float* conv2_w  = (const float*)d_in[7];
  const float* conv2_b  = (const float*)d_in[8];
  const float* bn2_g    = (const float*)d_in[9];
  const float* bn2_b    = (const float*)d_in[10];
  const float* se2_w1   = (const float*)d_in[11];
  const float* se2_w2   = (const float*)d_in[12];
  const float* review_w = (const float*)d_in[13];
  const float* review_b = (const float*)d_in[14];
  const float* final_w  = (const float*)d_in[15];
  const float* final_b  = (const float*)d_in[16];

  float* ws    = (float*)d_ws;
  float* x1buf = ws;                 // B*C1*HW floats (RAW conv1 output)
  float* stats = ws + X1_FLOATS;     // STATS_TOTAL floats
  float* out   = (float*)d_out;      // conv2 raw -> x2 in place; + 32 tail floats

  hipMemsetAsync(stats, 0, STATS_TOTAL * sizeof(float), stream);

  conv1_kernel<<<dim3(16, 16, B), 256, 0, stream>>>(
      x, conv1_w, conv1_b, x1buf, stats + OFF_BN1_SUM, stats + OFF_BN1_SQ);

  bnpool_kernel<<<dim3(8, C1, B), 256, 0, stream>>>(
      x1buf, stats, OFF_BN1_SUM, OFF_BN1_SQ, bn1_g, bn1_b, stats + OFF_POOL1, C1);

  se1_kernel<<<1, 64, 0, stream>>>(stats, se1_w1, se1_w2);

  conv2_kernel<<<dim3(16, 16, B), 256, 0, stream>>>(
      x1buf, conv2_w, conv2_b, stats, bn1_g, bn1_b, stats + OFF_S1,
      review_w, review_b,
      out, stats + OFF_BN2_SUM, stats + OFF_BN2_SQ, stats + OFF_REVSUM);

  bnpool_kernel<<<dim3(8, C2, B), 256, 0, stream>>>(
      out, stats, OFF_BN2_SUM, OFF_BN2_SQ, bn2_g, bn2_b, stats + OFF_POOL2, C2);

  se2_kernel<<<1, 64, 0, stream>>>(stats, se2_w1, se2_w2);

  apply2_kernel<<<dim3(16, C2, B), 256, 0, stream>>>(
      out, stats, bn2_g, bn2_b, stats + OFF_S2);

  final_kernel<<<1, 64, 0, stream>>>(stats, final_w, final_b, out + OUT_X2_FLOATS);
}